// Round 7
// baseline (960.235 us; speedup 1.0000x reference)
//
#include <hip/hip_runtime.h>
#include <stdint.h>

#define B_ 4
#define N_ 256
#define H_ 192
#define H3_ 576
#define F_ 64
#define SH_ 24      // hidden per slice (8 slices)
#define SC_ 72      // 3 gates * SH_

// ---- workspace layout (32-bit words) ----
// HL/SL (MALL) and FHL/FSL (fast, XCD-L2) rows are 192 tagged u64:
// high32 = tag (t+1), low32 = fp32 bits. Tags 1..256; 0xAAAAAAAA poison never matches.
#define H0_OFF   0u
#define ZC_OFF   1024u
#define HL_OFF   2048u        // MALL h_prov rows [b][t][192] u64
#define SL_OFF   395264u      // MALL S rows
#define AN_OFF   788480u      // [b][t][4] u64 ancestor masks
#define TG_OFF   796672u      // [b][t][4] u64 target masks
#define PL_OFF   804864u      // parent lists (u8)
#define PC_OFF   870400u      // parent counts
#define DG_OFF   871424u      // 1/deg
#define G_OFF    872448u      // G^T: [b][k][N]
#define C_OFF    1069056u     // Hprov@W1a + zc
#define CL_OFF   1265664u     // children lists (u8)
#define CC_OFF   1331200u     // children counts
#define XC_OFF   1332224u     // [b][16] xcd-id exchange words
#define FHL_OFF  1332288u     // fast (XCD-L2) h_prov rows
#define FSL_OFF  1725504u     // fast (XCD-L2) S rows

#define AN64 (AN_OFF/2)
#define TG64 (TG_OFF/2)

#define NF_OUT 262144u
#define LL_OUT 327680u

__device__ __forceinline__ float sigm_(float x){ return 1.0f/(1.0f + __expf(-x)); }
__device__ __forceinline__ float tanh_(float x){
  float ax = fabsf(x);
  float e = __expf(-2.0f*ax);
  float t = (1.0f - e)/(1.0f + e);
  return x < 0.0f ? -t : t;
}

// MALL (agent/sc1) tagged ops — proven r3-r6.
__device__ __forceinline__ void st_mall_(uint32_t* p, unsigned long long u){
  __hip_atomic_store((unsigned long long*)p, u, __ATOMIC_RELAXED, __HIP_MEMORY_SCOPE_AGENT);
}
__device__ __forceinline__ unsigned long long ld_mall_(const uint32_t* p){
  return __hip_atomic_load((const unsigned long long*)p, __ATOMIC_RELAXED, __HIP_MEMORY_SCOPE_AGENT);
}
// fast-path load: sc0 = L1-bypass read served by the XCD's shared L2.
__device__ __forceinline__ unsigned long long ld_l2_(const uint32_t* p){
  unsigned long long v;
  asm volatile("global_load_dwordx2 %0, %1, off sc0\n\ts_waitcnt vmcnt(0)"
               : "=v"(v) : "v"(p) : "memory");
  return v;
}
// dual publish: plain write-through store (own XCD L2) + sc1 store (MALL).
__device__ __forceinline__ void pub_(uint32_t* fp, uint32_t* mp, float v, uint32_t tag){
  unsigned long long u = ((unsigned long long)tag<<32) | (unsigned long long)__float_as_uint(v);
  __hip_atomic_store((unsigned long long*)fp, u, __ATOMIC_RELAXED, __HIP_MEMORY_SCOPE_WORKGROUP);
  st_mall_(mp, u);
}
// hang-proof hybrid poll: fast lanes spin on L2 copy, every 2nd iter also accept the
// MALL copy; non-fast lanes spin on MALL only. One u64 per lane per iteration.
__device__ __forceinline__ float pollH_(const uint32_t* fp, const uint32_t* mp, int fast, uint32_t tag){
  unsigned long long x = 0; int it = 0;
  for(;;){
    if (fast){
      x = ld_l2_(fp);
      if ((uint32_t)(x>>32) != tag && (((++it) & 1) != 0)){
        unsigned long long m = ld_mall_(mp);
        if ((uint32_t)(m>>32) == tag) x = m;
      }
    } else {
      x = ld_mall_(mp);
    }
    if (__all((int)((uint32_t)(x>>32) == tag))) break;
  }
  return __uint_as_float((uint32_t)x);
}

// ---------- pre1: (bx<N_): parent lists/bitmasks/deg | (bx==N_): h0, zc, ll=0 ----------
__global__ void __launch_bounds__(192) k_pre1(const float* __restrict__ z,
    const float* __restrict__ Winit, const float* __restrict__ binit,
    const float* __restrict__ W1, const float* __restrict__ b1,
    const float* __restrict__ tgt, float* ws, float* out)
{
  int bx = blockIdx.x, b = blockIdx.y, tid = threadIdx.x;
  if (bx == N_){
    __shared__ float zs[H_];
    zs[tid] = z[b*H_ + tid];
    __syncthreads();
    float a0=0.f, a1=0.f;
    for (int k=0;k<H_;k++){
      float zv = zs[k];
      a0 += zv * Winit[(size_t)k*H_ + tid];
      a1 += zv * W1[(size_t)(2*H_ + k)*H_ + tid];
    }
    ws[H0_OFF + b*H_ + tid] = tanh_(a0 + binit[tid]);
    ws[ZC_OFF + b*H_ + tid] = a1 + b1[tid];
    if (b==0 && tid==0) out[LL_OUT] = 0.0f;
    return;
  }
  if (tid >= 64) return;
  int t = bx, lane = tid;
  uint32_t* wsu = (uint32_t*)ws;
  unsigned long long* ws64 = (unsigned long long*)ws;
  const float* row = tgt + ((size_t)(b*N_) + t)*N_;
  uint8_t* pl = ((uint8_t*)&wsu[PL_OFF]) + (size_t)(b*N_ + t)*N_;
  int cnt = 0;
  #pragma unroll
  for (int m=0;m<4;m++){
    float v = row[m*64 + lane];
    bool p = (v != 0.0f);
    unsigned long long bw = __ballot(p);
    if (lane == 0) ws64[TG64 + (size_t)(b*N_+t)*4 + m] = bw;
    if (p){
      int pos = cnt + (int)__popcll(bw & ((1ULL<<lane)-1ULL));
      pl[pos] = (uint8_t)(m*64 + lane);
    }
    cnt += (int)__popcll(bw);
  }
  if (lane == 0){
    wsu[PC_OFF + b*N_ + t] = (uint32_t)cnt;
    ws[DG_OFF + b*N_ + t] = 1.0f / fmaxf((float)cnt, 1.0f);
  }
}

// ---------- pre2: children lists (transpose of parent lists) ----------
__global__ void __launch_bounds__(64) k_pre2(float* ws)
{
  int j = blockIdx.x, b = blockIdx.y, lane = threadIdx.x;
  uint32_t* wsu = (uint32_t*)ws;
  unsigned long long* ws64 = (unsigned long long*)ws;
  uint8_t* cl = ((uint8_t*)&wsu[CL_OFF]) + (size_t)(b*N_ + j)*N_;
  int w = j >> 6; int sb = j & 63;
  int cnt = 0;
  #pragma unroll
  for (int m=0;m<4;m++){
    int t = m*64 + lane;
    unsigned long long rowm = ws64[TG64 + (size_t)(b*N_+t)*4 + w];
    bool p = ((rowm >> sb) & 1ULL) != 0ULL;
    unsigned long long bw = __ballot(p);
    if (p){
      int pos = cnt + (int)__popcll(bw & ((1ULL<<lane)-1ULL));
      cl[pos] = (uint8_t)t;
    }
    cnt += (int)__popcll(bw);
  }
  if (lane == 0) wsu[CC_OFF + b*N_ + j] = (uint32_t)cnt;
}

// ---------- pass 1 ----------
// 512 threads, 8 slice-blocks per batch (grid 64 slots; b=bx&7, slice=bx>>3 -> all 8
// blocks of a batch on one XCD under round-robin dispatch). mv threads: hh=tid>>4 in
// [0,24), kc=tid&15; butterfly over the 16 kc lanes leaves full gate-col sums in every
// lane -> gates in-thread; 2 barriers/step. tid<192 polls element tid. Waves 6-7:
// delayed PS scatter + ancestor rows.
__global__ void __launch_bounds__(512) k_pass1(const float* __restrict__ z,
    const float* __restrict__ Wih, const float* __restrict__ Whh,
    const float* __restrict__ bih_g, const float* __restrict__ bhh_g,
    float* ws)
{
  int bx = blockIdx.x;
  int b = bx & 7;
  if (b >= B_) return;
  int slice = bx >> 3;      // 0..7
  int tid = threadIdx.x;
  float* wsf = ws;
  uint32_t* wsu = (uint32_t*)ws;
  unsigned long long* ws64 = (unsigned long long*)ws;

  __shared__ __align__(16) float sruns[H_];
  __shared__ __align__(16) float sh[H_];
  __shared__ __align__(16) float sPS[N_*SC_];
  __shared__ __align__(16) float sdelta[2][SC_];
  __shared__ int sfast[8];
  __shared__ unsigned long long sAB[N_][4];
  __shared__ float sDG[N_], sTF1[N_], sTF2[N_];

  const int hh = tid >> 4;      // 0..31; mv threads have hh<24
  const int kc = tid & 15;
  const bool mv = (hh < 24);

  // ---- XCD discovery + exchange (one-time; garbage-tolerant) ----
  uint32_t xcc = (uint32_t)__builtin_amdgcn_s_getreg((31u<<11) | 20u) & 15u;  // HW_REG_XCC_ID
  if (tid == 0)
    __hip_atomic_store(&wsu[XC_OFF + b*16 + slice], 0xC0DE0000u | xcc,
                       __ATOMIC_RELAXED, __HIP_MEMORY_SCOPE_AGENT);
  if (tid < 64){
    uint32_t v = 0; int ok;
    do {
      v = (tid < 8) ? __hip_atomic_load(&wsu[XC_OFF + b*16 + tid],
              __ATOMIC_RELAXED, __HIP_MEMORY_SCOPE_AGENT) : 0xC0DE0000u;
      ok = (int)((v >> 16) == 0xC0DEu);
    } while (!__all(ok));
    if (tid < 8) sfast[tid] = ((v & 0xFFu) == xcc) ? 1 : 0;
  }

  // ---- per-step scalar tables ----
  for (int i = tid; i < N_; i += 512){
    sDG[i] = wsf[DG_OFF + b*N_ + i];
    float f1 = 0.f, f2 = 0.f;
    if (i >= 1){
      unsigned long long w1 = ws64[TG64 + (size_t)(b*N_+i)*4 + ((i-1)>>6)];
      f1 = (float)((w1 >> ((i-1)&63)) & 1ULL);
    }
    if (i >= 2){
      unsigned long long w2 = ws64[TG64 + (size_t)(b*N_+i)*4 + ((i-2)>>6)];
      f2 = (float)((w2 >> ((i-2)&63)) & 1ULL);
    }
    sTF1[i] = f1; sTF2[i] = f2;
  }

  // ---- weights: thread (hh,kc) owns cols {g*192+slice*24+hh}, k in [kc*12,kc*12+12) ----
  float rwih[3][12], rwhh[3][12], rbih[3], rbhh[3], rghz[3];
  if (mv){
    #pragma unroll
    for (int g=0; g<3; g++){
      int col = g*H_ + slice*SH_ + hh;
      #pragma unroll
      for (int i=0;i<12;i++){
        rwih[g][i] = Wih[(size_t)(kc*12+i)*H3_ + col];
        rwhh[g][i] = Whh[(size_t)(kc*12+i)*H3_ + col];
      }
      rbih[g] = bih_g[col];
      rbhh[g] = bhh_g[col];
    }
    // ghz = z@W_hh + b_hh (butterfly over the 16 kc lanes of this hh group)
    float a0=0.f,a1=0.f,a2=0.f;
    #pragma unroll
    for (int i=0;i<12;i++){
      float zv = z[b*H_ + kc*12 + i];
      a0 += zv*rwhh[0][i]; a1 += zv*rwhh[1][i]; a2 += zv*rwhh[2][i];
    }
    #pragma unroll
    for (int m=1;m<16;m<<=1){
      a0 += __shfl_xor(a0,m); a1 += __shfl_xor(a1,m); a2 += __shfl_xor(a2,m);
    }
    rghz[0]=a0+rbhh[0]; rghz[1]=a1+rbhh[1]; rghz[2]=a2+rbhh[2];
  }
  float zreg = mv ? z[b*H_ + slice*SH_ + hh] : 0.0f;
  for (int i = tid; i < N_*SC_; i += 512) sPS[i] = 0.0f;
  if (tid >= 384 && tid < 388) sAB[0][tid-384] = 0ULL;
  // publish S(0) (tag 1)
  if (mv && kc == 0){
    float v = wsf[H0_OFF + b*H_ + slice*SH_ + hh];
    int e = slice*SH_ + hh;
    pub_(&wsu[FSL_OFF + (unsigned)(b*N_)*384u + 2u*e],
         &wsu[SL_OFF  + (unsigned)(b*N_)*384u + 2u*e], v, 1u);
  }
  __syncthreads();

  const int fastf = (tid < 192) ? sfast[tid/SH_] : 0;
  float rsum = 0.f;
  float qp0=0.f,qp1=0.f,qp2=0.f, dp0=0.f,dp1=0.f,dp2=0.f;

  for (int t=1; t<N_; t++){
    const uint32_t tagS = (uint32_t)t;
    const uint32_t tagH = (uint32_t)(t+1);
    // P1: poll S(t-1) element tid
    if (tid < 192){
      float v = pollH_(&wsu[FSL_OFF + (unsigned)(b*N_+(t-1))*384u + 2u*(unsigned)tid],
                       &wsu[SL_OFF  + (unsigned)(b*N_+(t-1))*384u + 2u*(unsigned)tid],
                       fastf, tagS);
      rsum += v;
      sruns[tid] = rsum;
    }
    __syncthreads();   // B1
    float hp=0.f, a20=0.f, a21=0.f, a22=0.f;
    if (mv){
      float dginv = sDG[t], tf1 = sTF1[t], tf2 = sTF2[t];
      // mv1: q (3 cols) over k-chunk kc, butterfly -> full sums in all lanes
      float x[12];
      *(float4*)&x[0] = *(float4*)&sruns[kc*12];
      *(float4*)&x[4] = *(float4*)&sruns[kc*12+4];
      *(float4*)&x[8] = *(float4*)&sruns[kc*12+8];
      float q0=0.f,q1=0.f,q2=0.f;
      #pragma unroll
      for (int i=0;i<12;i++){
        q0 += x[i]*rwih[0][i]; q1 += x[i]*rwih[1][i]; q2 += x[i]*rwih[2][i];
      }
      #pragma unroll
      for (int m=1;m<16;m<<=1){
        q0 += __shfl_xor(q0,m); q1 += __shfl_xor(q1,m); q2 += __shfl_xor(q2,m);
      }
      float d0=q0-qp0, d1=q1-qp1, d2=q2-qp2;
      qp0=q0; qp1=q1; qp2=q2;
      if (kc == 0){
        sdelta[t&1][0*SH_+hh]=d0; sdelta[t&1][1*SH_+hh]=d1; sdelta[t&1][2*SH_+hh]=d2;
      }
      float pv0 = sPS[t*SC_ + 0*SH_ + hh];
      float pv1 = sPS[t*SC_ + 1*SH_ + hh];
      float pv2 = sPS[t*SC_ + 2*SH_ + hh];
      a20 = (pv0 + tf1*d0 + tf2*dp0)*dginv + rbih[0];
      a21 = (pv1 + tf1*d1 + tf2*dp1)*dginv + rbih[1];
      a22 = (pv2 + tf1*d2 + tf2*dp2)*dginv + rbih[2];
      dp0=d0; dp1=d1; dp2=d2;
      float invt = 1.0f/(float)t;
      float a10 = q0*invt + rbih[0];
      float a11 = q1*invt + rbih[1];
      float a12 = q2*invt + rbih[2];
      // gates1 in-thread
      float r = sigm_(a10 + rghz[0]);
      float u = sigm_(a11 + rghz[1]);
      float n = tanh_(a12 + r*rghz[2]);
      hp = (1.0f-u)*n + u*zreg;
      if (kc == 0){
        int e = slice*SH_ + hh;
        pub_(&wsu[FHL_OFF + (unsigned)(b*N_+t)*384u + 2u*e],
             &wsu[HL_OFF  + (unsigned)(b*N_+t)*384u + 2u*e], hp, tagH);
      }
      // P3: poll H(t) element tid (pollers are a subset of mv threads)
      if (tid < 192){
        float hv = pollH_(&wsu[FHL_OFF + (unsigned)(b*N_+t)*384u + 2u*(unsigned)tid],
                          &wsu[HL_OFF  + (unsigned)(b*N_+t)*384u + 2u*(unsigned)tid],
                          fastf, tagH);
        sh[tid] = hv;
      }
    } else {
      int lane = tid - 384;
      if (lane < SC_){
        // delayed scatter: delta computed at step t-1 (= node t-2) -> children rows > t
        if (t >= 2){
          int node = t-2;
          int ccn = (int)wsu[CC_OFF + b*N_ + node];
          const uint8_t* cl = ((const uint8_t*)&wsu[CL_OFF]) + (size_t)(b*N_ + node)*N_;
          float dd = sdelta[(t-1)&1][lane];
          for (int i=0;i<ccn;i++){
            int tc = cl[i];
            if (tc > t) sPS[tc*SC_ + lane] += dd;
          }
        }
      } else if (lane < SC_+4){
        // ancestor row t (private per block; slice 0 exports)
        int w = lane - SC_;
        int npt = (int)wsu[PC_OFF + b*N_ + t];
        const uint8_t* pb = ((const uint8_t*)&wsu[PL_OFF]) + (size_t)(b*N_ + t)*N_;
        unsigned long long acc = 0ULL;
        for (int i=0;i<npt;i++) acc |= sAB[pb[i]][w];
        if (slice == 0) ws64[AN64 + (size_t)(b*N_+t)*4 + w] = acc;
        sAB[t][w] = acc | ws64[TG64 + (size_t)(b*N_+t)*4 + w];
      }
    }
    __syncthreads();   // B2
    if (mv){
      // mv2: gh2 (3 cols) from full h_prov
      float x[12];
      *(float4*)&x[0] = *(float4*)&sh[kc*12];
      *(float4*)&x[4] = *(float4*)&sh[kc*12+4];
      *(float4*)&x[8] = *(float4*)&sh[kc*12+8];
      float y0=0.f,y1=0.f,y2=0.f;
      #pragma unroll
      for (int i=0;i<12;i++){
        y0 += x[i]*rwhh[0][i]; y1 += x[i]*rwhh[1][i]; y2 += x[i]*rwhh[2][i];
      }
      #pragma unroll
      for (int m=1;m<16;m<<=1){
        y0 += __shfl_xor(y0,m); y1 += __shfl_xor(y1,m); y2 += __shfl_xor(y2,m);
      }
      // gates2 in-thread
      float r2 = sigm_(a20 + y0 + rbhh[0]);
      float u2 = sigm_(a21 + y1 + rbhh[1]);
      float n2 = tanh_(a22 + r2*(y2 + rbhh[2]));
      float hn = (1.0f-u2)*n2 + u2*hp;
      if (kc == 0){
        int e = slice*SH_ + hh;
        pub_(&wsu[FSL_OFF + (unsigned)(b*N_+t)*384u + 2u*e],
             &wsu[SL_OFF  + (unsigned)(b*N_+t)*384u + 2u*e], hn, tagH);
      }
    }
  }
}

// ---------- pass 2a: G^T = (S@W1b)^T, C = Hprov@W1a + zc, NF = S@Wf + bf ----------
__global__ void k_p2a(const float* __restrict__ W1, const float* __restrict__ Wf,
    const float* __restrict__ bf, float* ws, float* out)
{
  int j = blockIdx.x, b = blockIdx.y, tid = threadIdx.x;
  __shared__ float srow[H_], hrow[H_];
  __shared__ float nfp[3][F_];
  srow[tid] = ws[SL_OFF + (unsigned)(b*N_+j)*384u + 2u*tid];
  hrow[tid] = ws[HL_OFF + (unsigned)(b*N_+j)*384u + 2u*tid];   // garbage for j=0, C[0] unused
  __syncthreads();
  float accG = 0.f, accC = 0.f;
  for (int k=0;k<H_;k++){
    float sv = srow[k], hv = hrow[k];
    accG += sv * W1[(size_t)(H_+k)*H_ + tid];
    accC += hv * W1[(size_t)k*H_ + tid];
  }
  ws[G_OFF + ((size_t)b*H_ + tid)*N_ + j] = accG;    // transposed store
  ws[C_OFF + (size_t)(b*N_+j)*H_ + tid] = accC + ws[ZC_OFF + b*H_ + tid];
  int f = tid & 63, kp = tid >> 6;
  float a = 0.f;
  for (int i=0;i<64;i++){ int k = kp*64 + i; a += srow[k]*Wf[(size_t)k*F_ + f]; }
  nfp[kp][f] = a;
  __syncthreads();
  if (tid < F_) out[NF_OUT + (size_t)(b*N_+j)*F_ + tid] = nfp[0][tid]+nfp[1][tid]+nfp[2][tid] + bf[tid];
}

// ---------- pass 2b: log-likelihood, lane-per-candidate-parent ----------
__global__ void __launch_bounds__(256) k_p2b(const float* __restrict__ W2,
    const float* __restrict__ b2p, float* ws, float* out)
{
  int t = blockIdx.x + 1, b = blockIdx.y;
  int tid = threadIdx.x; int lane = tid & 63; int wv = tid >> 6;
  __shared__ float cv[H_], w2s[H_];
  __shared__ float wsum[4];
  unsigned long long* ws64 = (unsigned long long*)ws;
  if (tid < H_){
    cv[tid] = ws[C_OFF + (size_t)(b*N_+t)*H_ + tid];
    w2s[tid] = W2[tid];
  }
  __syncthreads();
  float acc = 0.f;
  if (tid < t){
    const float* GT = ws + G_OFF + (size_t)b*H_*N_;
    float a = 0.f;
    for (int k=0;k<H_;k++) a += fmaxf(cv[k] + GT[(size_t)k*N_ + tid], 0.f) * w2s[k];
    float logit = a + b2p[0];
    float pp = 1.0f/(1.0f+__expf(-logit));
    unsigned long long an = ws64[AN64 + (size_t)(b*N_+t)*4 + (tid>>6)];
    unsigned long long tg = ws64[TG64 + (size_t)(b*N_+t)*4 + (tid>>6)];
    float anc = (float)((an >> (tid&63)) & 1ULL);
    pp = pp * (1.0f - anc);
    pp = fminf(fmaxf(pp, 1e-6f), 1.0f - 1e-6f);
    int tgb = (int)((tg >> (tid&63)) & 1ULL);
    acc = tgb ? logf(pp) : log1pf(-pp);
  }
  #pragma unroll
  for (int m=32;m>=1;m>>=1) acc += __shfl_xor(acc, m);
  if (lane == 0) wsum[wv] = acc;
  __syncthreads();
  if (tid == 0) atomicAdd(out + LL_OUT, wsum[0]+wsum[1]+wsum[2]+wsum[3]);
}

extern "C" void kernel_launch(void* const* d_in, const int* in_sizes, int n_in,
                              void* d_out, int out_size, void* d_ws, size_t ws_size,
                              hipStream_t stream) {
  (void)in_sizes; (void)n_in; (void)out_size; (void)ws_size;
  const float* z     = (const float*)d_in[0];
  const float* tgt   = (const float*)d_in[1];
  const float* Winit = (const float*)d_in[2];
  const float* binit = (const float*)d_in[3];
  const float* Wih   = (const float*)d_in[4];
  const float* Whh   = (const float*)d_in[5];
  const float* bih   = (const float*)d_in[6];
  const float* bhh   = (const float*)d_in[7];
  const float* W1    = (const float*)d_in[8];
  const float* b1    = (const float*)d_in[9];
  const float* W2    = (const float*)d_in[10];
  const float* b2    = (const float*)d_in[11];
  const float* Wf    = (const float*)d_in[12];
  const float* bf    = (const float*)d_in[13];
  float* out = (float*)d_out;
  float* ws  = (float*)d_ws;

  hipMemcpyAsync(d_out, d_in[1], (size_t)B_*N_*N_*sizeof(float), hipMemcpyDeviceToDevice, stream);

  k_pre1<<<dim3(N_+1, B_), dim3(192), 0, stream>>>(z, Winit, binit, W1, b1, tgt, ws, out);
  k_pre2<<<dim3(N_, B_), dim3(64), 0, stream>>>(ws);
  k_pass1<<<dim3(64), dim3(512), 0, stream>>>(z, Wih, Whh, bih, bhh, ws);
  k_p2a<<<dim3(N_, B_), dim3(H_), 0, stream>>>(W1, Wf, bf, ws, out);
  k_p2b<<<dim3(N_-1, B_), dim3(256), 0, stream>>>(W2, b2, ws, out);
}